// Round 1
// baseline (218.877 us; speedup 1.0000x reference)
//
#include <hip/hip_runtime.h>

// MXFP (e2m1, group=32) quantize-dequantize of f32 tensor [4,32,2048,128].
// Bit-exact vs reference (R0/R1: absmax 0.0).
//
// R3 theory: all top-5 rocprof dispatches are 80us harness poison fills
// (512 MiB @ 6.6 TB/s each); our kernel is <80us. Traffic floor is
// 268.4 MB @ 6.29 TB/s (copy ubench) = 42.7us. This round discriminates
// "kernel already ~46us (roofline)" vs "kernel ~70us (MLP-limited)":
//   - 8 float4 tiles per thread (was 4): 128 B/lane of loads in flight
//   - in-place tile compute (v[k] = mxfp_tile(v[k])): live set stays
//     ~32 data VGPRs -> no occupancy loss
//   - fused compute+store loop: store of tile k issues under the counted
//     vmcnt wait of tile k+1..7 (read/write streams overlap per-wave)
//   - NT load+store retained: 512 MiB poison fills wash L3 every
//     iteration, so there is no input residency to exploit
// Prediction: dur_us unchanged (within noise) if already at roofline,
// else -10..-25us. absmax stays 0.0.

typedef float f32x4 __attribute__((ext_vector_type(4)));

__device__ __forceinline__ float mxfp_elem(float xd, float scale) {
    // xd = x * 2^-se (exact). Quantize to e2m1 (RNE), dequant by scale.
    float ax = fabsf(xd);
    unsigned b = __float_as_uint(ax);
    int e2 = (int)(b >> 23) - 127;                               // floor(log2 ax)
    float m = __uint_as_float((b & 0x007FFFFFu) | 0x3F800000u);  // mant in [1,2)
    float q = rintf(m * 2.0f);                                   // RNE -> {2,3,4}
    float x_rnd = q * __uint_as_float((unsigned)(e2 + 126) << 23); // q*2^(e2-1)
    float xc = fminf(fmaxf(x_rnd, 0.5f), 6.0f);                  // clamp
    float r = copysignf(xc, xd);
    r = (ax <= 0.25f) ? 0.0f : r;                                // flush-to-zero
    return r * scale;                                            // exact pow2 mul
}

__device__ __forceinline__ f32x4 mxfp_tile(f32x4 v) {
    // group of 32 = 8 consecutive lanes; butterfly max over them
    float amax = fmaxf(fmaxf(fabsf(v.x), fabsf(v.y)),
                       fmaxf(fabsf(v.z), fabsf(v.w)));
    amax = fmaxf(amax, __shfl_xor(amax, 1, 64));
    amax = fmaxf(amax, __shfl_xor(amax, 2, 64));
    amax = fmaxf(amax, __shfl_xor(amax, 4, 64));
    if (amax == 0.0f) amax = 1.0f;          // reference: where(max==0, 1, max)

    int se = ((int)(__float_as_uint(amax) >> 23) - 127) - 2;  // floor(log2)-2
    se = se < -126 ? -126 : (se > 127 ? 127 : se);            // keep normal
    float scale     = __uint_as_float((unsigned)(se + 127) << 23);  // 2^se
    float inv_scale = __uint_as_float((unsigned)(127 - se) << 23);  // 2^-se

    f32x4 o;
    o.x = mxfp_elem(v.x * inv_scale, scale);
    o.y = mxfp_elem(v.y * inv_scale, scale);
    o.z = mxfp_elem(v.z * inv_scale, scale);
    o.w = mxfp_elem(v.w * inv_scale, scale);
    return o;
}

__global__ __launch_bounds__(256) void
mxfp_quant_kernel(const float* __restrict__ x, float* __restrict__ out, int n4) {
    const f32x4* __restrict__ x4 = (const f32x4*)x;
    f32x4* __restrict__ o4 = (f32x4*)out;

    // Each block owns a contiguous tile of 2048 float4s; each thread handles
    // 8 float4s at stride 256 (keeps 8-lane group alignment + coalescing).
    int base = blockIdx.x * 2048 + (int)threadIdx.x;

    if (base + 7 * 256 < n4) {
        f32x4 v[8];  // fully unrolled -> compile-time indexed, stays in VGPRs
        #pragma unroll
        for (int k = 0; k < 8; ++k)
            v[k] = __builtin_nontemporal_load(&x4[base + 256 * k]);
        // compute+store fused: store of tile k issues while loads k+1..7
        // are still outstanding (counted vmcnt waits, no full drain)
        #pragma unroll
        for (int k = 0; k < 8; ++k) {
            v[k] = mxfp_tile(v[k]);
            __builtin_nontemporal_store(v[k], &o4[base + 256 * k]);
        }
    } else {
        // generic tail (unused for the bench shape: n4 = 8192*1024 exactly)
        for (int k = 0; k < 8; ++k) {
            int idx = base + 256 * k;
            if (idx < n4) {
                f32x4 o = mxfp_tile(x4[idx]);
                __builtin_nontemporal_store(o, &o4[idx]);
            }
        }
    }
}

extern "C" void kernel_launch(void* const* d_in, const int* in_sizes, int n_in,
                              void* d_out, int out_size, void* d_ws, size_t ws_size,
                              hipStream_t stream) {
    const float* x = (const float*)d_in[0];
    float* out = (float*)d_out;
    int n = in_sizes[0];        // 33,554,432
    int n4 = n / 4;             // 8,388,608 float4s
    int block = 256;
    int grid = (n4 + 2047) / 2048;   // 8 float4s per thread -> 4096 blocks
    mxfp_quant_kernel<<<grid, block, 0, stream>>>(x, out, n4);
}